// Round 10
// baseline (214.740 us; speedup 1.0000x reference)
//
#include <hip/hip_runtime.h>
#include <stdint.h>

#define B_ 2
#define S_ 1024
#define D_ 768
#define H_ 12
#define DH 64
#define G_ 4
#define DG 192
#define T_ 2047
#define SCALEF 0.125f

typedef unsigned short u16;
typedef unsigned int u32;
typedef __attribute__((ext_vector_type(8))) short short8;
typedef __attribute__((ext_vector_type(4))) float floatx4;

__device__ __forceinline__ float uas(u32 x){ union { u32 i; float f; } v; v.i = x; return v.f; }
__device__ __forceinline__ float bf2f(u16 u){ return uas(((u32)u) << 16); }
__device__ __forceinline__ u16 f2bf(float f){
    union { float f; u32 i; } v; v.f = f;
    u32 x = v.i;
    u32 r = (x + 0x7fffu + ((x >> 16) & 1u)) >> 16;  // RNE
    return (u16)r;
}

// ---------------- Prep 1: fp32 -> bf16 copies (query -> qb, pe -> peb) ----------------
__global__ __launch_bounds__(256) void conv_kernel(
    const float* __restrict__ query, const float* __restrict__ pe,
    u16* __restrict__ qb, u16* __restrict__ peb)
{
    int t = blockIdx.x*256 + threadIdx.x;       // 196608 threads
    #pragma unroll
    for (int p = 0; p < 2; p++) {
        int u = t + p*196608;                   // query: 393216 float4 units
        float4 v = *(const float4*)(query + (size_t)u*4);
        union { u16 h[4]; uint2 w; } o;
        o.h[0]=f2bf(v.x); o.h[1]=f2bf(v.y); o.h[2]=f2bf(v.z); o.h[3]=f2bf(v.w);
        *(uint2*)(qb + (size_t)u*4) = o.w;
    }
    #pragma unroll
    for (int p = 0; p < 2; p++) {
        int u = t + p*196608;                   // pe: 393024 units (2047*768/4)
        if (u < 393024) {
            float4 v = *(const float4*)(pe + (size_t)u*4);
            union { u16 h[4]; uint2 w; } o;
            o.h[0]=f2bf(v.x); o.h[1]=f2bf(v.y); o.h[2]=f2bf(v.z); o.h[3]=f2bf(v.w);
            *(uint2*)(peb + (size_t)u*4) = o.w;
        }
    }
}

// ---------------- Prep 2: transpose-convert W matrices to bf16 [n][k] ----------------
// z=0: rk(768x768)->rkT  z=1: Wo->WoT  z=2/3/4: Wq/Wk/Wv grouped (4x 192x192)
__global__ __launch_bounds__(256) void trans_kernel(
    const float* __restrict__ rk, const float* __restrict__ Wo,
    const float* __restrict__ Wq, const float* __restrict__ Wk, const float* __restrict__ Wv,
    u16* __restrict__ rkT, u16* __restrict__ WoT,
    u16* __restrict__ WqT, u16* __restrict__ WkT, u16* __restrict__ WvT)
{
    __shared__ u16 T[64][72];
    int tid = threadIdx.x;
    int z = blockIdx.z;
    int tx = blockIdx.x, ty = blockIdx.y;
    const float* src; u16* dst; int KN;
    if (z == 0)      { src = rk; dst = rkT; KN = 768; }
    else if (z == 1) { src = Wo; dst = WoT; KN = 768; }
    else {
        if (tx >= 3) return;
        const float* W3[3] = {Wq, Wk, Wv};
        u16* D3[3] = {WqT, WkT, WvT};
        int gg = ty / 3; ty = ty % 3;
        src = W3[z-2] + (size_t)gg*DG*DG;
        dst = D3[z-2] + (size_t)gg*DG*DG;
        KN = 192;
    }
    int k0 = tx*64, n0 = ty*64;
    int r = tid >> 2, c0 = (tid & 3) * 16;
    #pragma unroll
    for (int q = 0; q < 4; q++) {
        float4 v = *(const float4*)(src + (size_t)(k0+r)*KN + n0 + c0 + q*4);
        T[c0+q*4+0][r] = f2bf(v.x);
        T[c0+q*4+1][r] = f2bf(v.y);
        T[c0+q*4+2][r] = f2bf(v.z);
        T[c0+q*4+3][r] = f2bf(v.w);
    }
    __syncthreads();
    int n = tid >> 2, kc0 = (tid & 3) * 16;
    uint4 w0 = *(uint4*)&T[n][kc0];
    uint4 w1 = *(uint4*)&T[n][kc0 + 8];
    *(uint4*)(dst + (size_t)(n0+n)*KN + k0 + kc0)     = w0;
    *(uint4*)(dst + (size_t)(n0+n)*KN + k0 + kc0 + 8) = w1;
}

// ---------------- Kernel A: bf16 MFMA grouped q/k/v projections ----------------
// A from qb (bf16), weights from pre-transposed WqT/WkT/WvT. Chunked LDS [ko][m][8].
__global__ __launch_bounds__(256) void proj_kernel(
    const u16* __restrict__ qb,
    const u16* __restrict__ WqT, const u16* __restrict__ WkT, const u16* __restrict__ WvT,
    const float* __restrict__ bk, const float* __restrict__ bv,
    u16* __restrict__ qq, u16* __restrict__ ko, u16* __restrict__ vt)
{
    __shared__ u16 As[8][64][8];
    __shared__ u16 Ws[3][8][64][8];
    int tid  = threadIdx.x;
    int wave = tid >> 6, lane = tid & 63;
    int qm   = lane & 15;
    int quad = lane >> 4;
    int m0 = blockIdx.x * 64;
    int g  = blockIdx.y / 3;
    int n0 = (blockIdx.y % 3) * 64;
    int mA = tid & 63, ko0 = tid >> 6;

    const u16* Abase = qb + (size_t)(m0 + mA)*D_ + g*DG;
    const u16* Wb[3] = {
        WqT + (size_t)g*DG*DG + (size_t)(n0 + mA)*DG,
        WkT + (size_t)g*DG*DG + (size_t)(n0 + mA)*DG,
        WvT + (size_t)g*DG*DG + (size_t)(n0 + mA)*DG };

    short8 ra[2], rw[3][2];
    ra[0] = *(const short8*)(Abase + ko0*8);
    ra[1] = *(const short8*)(Abase + (ko0+4)*8);
    #pragma unroll
    for (int md = 0; md < 3; md++) {
        rw[md][0] = *(const short8*)(Wb[md] + ko0*8);
        rw[md][1] = *(const short8*)(Wb[md] + (ko0+4)*8);
    }

    floatx4 acc[3][4];
    #pragma unroll
    for (int md = 0; md < 3; md++)
        #pragma unroll
        for (int bt = 0; bt < 4; bt++) acc[md][bt] = (floatx4){0.f,0.f,0.f,0.f};

    for (int kt = 0; kt < 3; kt++) {
        __syncthreads();
        *(short8*)&As[ko0][mA][0]   = ra[0];
        *(short8*)&As[ko0+4][mA][0] = ra[1];
        #pragma unroll
        for (int md = 0; md < 3; md++) {
            *(short8*)&Ws[md][ko0][mA][0]   = rw[md][0];
            *(short8*)&Ws[md][ko0+4][mA][0] = rw[md][1];
        }
        __syncthreads();
        if (kt < 2) {
            int k0 = (kt + 1) * 64;
            ra[0] = *(const short8*)(Abase + k0 + ko0*8);
            ra[1] = *(const short8*)(Abase + k0 + (ko0+4)*8);
            #pragma unroll
            for (int md = 0; md < 3; md++) {
                rw[md][0] = *(const short8*)(Wb[md] + k0 + ko0*8);
                rw[md][1] = *(const short8*)(Wb[md] + k0 + (ko0+4)*8);
            }
        }
        #pragma unroll
        for (int ks = 0; ks < 2; ks++) {
            short8 a = *(const short8*)&As[ks*4 + quad][wave*16 + qm][0];
            #pragma unroll
            for (int md = 0; md < 3; md++) {
                #pragma unroll
                for (int bt = 0; bt < 4; bt++) {
                    short8 b = *(const short8*)&Ws[md][ks*4 + quad][bt*16 + qm][0];
                    acc[md][bt] = __builtin_amdgcn_mfma_f32_16x16x32_bf16(a, b, acc[md][bt], 0,0,0);
                }
            }
        }
    }

    int rowbase = m0 + wave*16 + quad*4;
    int b  = rowbase >> 10;
    int s0 = rowbase & 1023;
    #pragma unroll
    for (int bt = 0; bt < 4; bt++) {
        int c = g*DG + n0 + bt*16 + qm;
        int n = c >> 6, d = c & 63;
        int bn = b*H_ + n;
        float bkv = bk[c], bvv = bv[c];
        #pragma unroll
        for (int gg = 0; gg < 4; gg++) {
            size_t o = ((size_t)bn*S_ + s0 + gg)*DH + d;
            qq[o] = f2bf(acc[0][bt][gg]*SCALEF);
            ko[o] = f2bf(acc[1][bt][gg] + bkv);
        }
        union { u16 h[4]; uint2 v; } vv;
        #pragma unroll
        for (int gg = 0; gg < 4; gg++) vv.h[gg] = f2bf(acc[2][bt][gg] + bvv);
        *(uint2*)(vt + ((size_t)bn*DH + d)*S_ + s0) = vv.v;
    }
}

// ---------------- Shared bf16 GEMM: C[M,768] = A[M,768] @ WT[768,768]^T ----------------
// Chunked LDS [ko][row][8]; reg-prefetch next K-slice. K=768 fixed (12 x BK=64).
// EPI 0: bf16 R[((c>>6)*T + row)*64 + (c&63)], guard row < Mvalid.
// EPI 1: fp32 outf = acc + bias + resid.
template<int EPI>
__global__ __launch_bounds__(256) void gemm_kernel(
    const u16* __restrict__ A, const u16* __restrict__ WT,
    const float* __restrict__ bias, const float* __restrict__ resid,
    u16* __restrict__ outb, float* __restrict__ outf, int Mvalid)
{
    __shared__ u16 As[8][64][8];
    __shared__ u16 Ws[8][64][8];
    int tid  = threadIdx.x;
    int wave = tid >> 6, lane = tid & 63;
    int qm   = lane & 15;
    int quad = lane >> 4;
    int m0 = blockIdx.x * 64;
    int n0 = blockIdx.y * 64;
    int mA = tid & 63, ko0 = tid >> 6;

    int rowA = m0 + mA; if (rowA >= Mvalid) rowA = Mvalid - 1;
    const u16* Abase = A  + (size_t)rowA*D_;
    const u16* Wbase = WT + (size_t)(n0 + mA)*D_;

    short8 ra[2], rw[2];
    ra[0] = *(const short8*)(Abase + ko0*8);
    ra[1] = *(const short8*)(Abase + (ko0+4)*8);
    rw[0] = *(const short8*)(Wbase + ko0*8);
    rw[1] = *(const short8*)(Wbase + (ko0+4)*8);

    floatx4 acc[4];
    #pragma unroll
    for (int t = 0; t < 4; t++) acc[t] = (floatx4){0.f,0.f,0.f,0.f};

    for (int kt = 0; kt < 12; kt++) {
        __syncthreads();
        *(short8*)&As[ko0][mA][0]   = ra[0];
        *(short8*)&As[ko0+4][mA][0] = ra[1];
        *(short8*)&Ws[ko0][mA][0]   = rw[0];
        *(short8*)&Ws[ko0+4][mA][0] = rw[1];
        __syncthreads();
        if (kt < 11) {
            int k0 = (kt + 1) * 64;
            ra[0] = *(const short8*)(Abase + k0 + ko0*8);
            ra[1] = *(const short8*)(Abase + k0 + (ko0+4)*8);
            rw[0] = *(const short8*)(Wbase + k0 + ko0*8);
            rw[1] = *(const short8*)(Wbase + k0 + (ko0+4)*8);
        }
        #pragma unroll
        for (int ks = 0; ks < 2; ks++) {
            short8 a = *(const short8*)&As[ks*4 + quad][wave*16 + qm][0];
            #pragma unroll
            for (int bt = 0; bt < 4; bt++) {
                short8 b = *(const short8*)&Ws[ks*4 + quad][bt*16 + qm][0];
                acc[bt] = __builtin_amdgcn_mfma_f32_16x16x32_bf16(a, b, acc[bt], 0,0,0);
            }
        }
    }

    #pragma unroll
    for (int bt = 0; bt < 4; bt++) {
        int c = n0 + bt*16 + qm;
        #pragma unroll
        for (int g = 0; g < 4; g++) {
            int row = m0 + wave*16 + quad*4 + g;
            if (EPI == 0) {
                if (row < Mvalid)
                    outb[((size_t)(c >> 6)*T_ + row)*DH + (c & 63)] = f2bf(acc[bt][g]);
            } else {
                outf[(size_t)row*D_ + c] = acc[bt][g] + bias[c] + resid[(size_t)row*D_ + c];
            }
        }
    }
}

// ---------------- Kernel C: MFMA fused rel-attention v4 (unchanged, verified) ----------------
__global__ __launch_bounds__(256, 2) void attn_kernel(
    const u16* __restrict__ qq,
    const u16* __restrict__ kk, const u16* __restrict__ vt,
    const u16* __restrict__ R,
    const float* __restrict__ rwb, const float* __restrict__ rrb,
    u16* __restrict__ av)
{
    __shared__ char smem[64*1024];
    u16* SC  = (u16*)smem;            // [16][1024] content scores -> probs
    u16* PSC = (u16*)(smem + 32768);  // [16][1024] pos scores
    int tid  = threadIdx.x;
    int wave = tid >> 6, lane = tid & 63;
    int qm   = lane & 15;
    int quad = lane >> 4;
    int k8   = quad * 8;
    int blkid = blockIdx.x;
    int xcd = blkid & 7;
    int sl  = blkid >> 3;
    int it  = sl & 63;
    int seg = sl >> 6;
    int bn  = xcd + 8*seg;
    int b = bn / H_, n = bn % H_;
    int i0 = it * 16;
    size_t hbase = (size_t)bn * S_ * DH;

    short8 qcf[2], qpf[2];
    #pragma unroll
    for (int s = 0; s < 2; s++) {
        const u16* qptr = qq + hbase + (size_t)(i0 + qm)*DH + s*32 + k8;
        const float* rwp = rwb + n*DH + s*32 + k8;
        const float* rrp = rrb + n*DH + s*32 + k8;
        #pragma unroll
        for (int j = 0; j < 8; j++) {
            float qv = bf2f(qptr[j]);
            qcf[s][j] = (short)f2bf(qv + rwp[j]*SCALEF);
            qpf[s][j] = (short)f2bf(qv + rrp[j]*SCALEF);
        }
    }

    {
        const u16* kbb = kk + hbase + (size_t)qm*DH + k8;
        short8 rb[8][2];
        #pragma unroll
        for (int t = 0; t < 8; t++) {
            const u16* kp = kbb + (size_t)((wave*16 + t)*16)*DH;
            rb[t][0] = *(const short8*)(kp);
            rb[t][1] = *(const short8*)(kp + 32);
        }
        #pragma unroll
        for (int t = 0; t < 16; t++) {
            short8 b0 = rb[t & 7][0], b1 = rb[t & 7][1];
            if (t < 8) {
                const u16* kp = kbb + (size_t)((wave*16 + t + 8)*16)*DH;
                rb[t & 7][0] = *(const short8*)(kp);
                rb[t & 7][1] = *(const short8*)(kp + 32);
            }
            floatx4 acc = {0.f,0.f,0.f,0.f};
            acc = __builtin_amdgcn_mfma_f32_16x16x32_bf16(qcf[0], b0, acc, 0,0,0);
            acc = __builtin_amdgcn_mfma_f32_16x16x32_bf16(qcf[1], b1, acc, 0,0,0);
            int j0 = (wave*16 + t) * 16;
            #pragma unroll
            for (int g = 0; g < 4; g++)
                SC[(quad*4 + g)*1024 + j0 + qm] = f2bf(acc[g]);
        }
    }

    int ubase = 1008 - i0;
    {
        const u16* rbb = R + (size_t)n*T_*DH + k8;
        short8 rb[8][2];
        int us[8];
        #pragma unroll
        for (int t = 0; t < 8; t++) {
            int m = t*4 + wave;
            int uu = ubase + m*16 + qm;
            int ur = (uu <= 2046) ? uu : 2046;
            us[t] = uu;
            const u16* rp = rbb + (size_t)ur*DH;
            rb[t][0] = *(const short8*)(rp);
            rb[t][1] = *(const short8*)(rp + 32);
        }
        #pragma unroll
        for (int t = 0; t < 16; t++) {
            short8 b0 = rb[t & 7][0], b1 = rb[t & 7][1];
            int uu = us[t & 7];
            if (t < 8) {
                int m2 = (t + 8)*4 + wave;
                int uu2 = ubase + m2*16 + qm;
                int ur2 = (uu2 <= 2046) ? uu2 : 2046;
                us[t & 7] = uu2;
                const u16* rp = rbb + (size_t)ur2*DH;
                rb[t & 7][0] = *(const short8*)(rp);
                rb[t & 7][1] = *(const short8*)(rp + 32);
            }
            floatx4 acc = {0.f,0.f,0.f,0.f};
            acc = __builtin_amdgcn_mfma_f32_16x16x32_bf16(qpf[0], b0, acc, 0,0,0);
            acc = __builtin_amdgcn_mfma_f32_16x16x32_bf16(qpf[1], b1, acc, 0,0,0);
            #pragma unroll
            for (int g = 0; g < 4; g++) {
                int row = quad*4 + g;
                int j = uu + i0 + row - 1024;
                if (j >= 0 && j < S_ && uu <= 2046)
                    PSC[row*1024 + j] = f2bf(acc[g]);
            }
        }
    }
    if (wave == 0) {
        int uu = ubase + 64*16 + qm;
        int ur = (uu <= 2046) ? uu : 2046;
        const u16* rp = R + ((size_t)n*T_ + ur)*DH + k8;
        short8 b0 = *(const short8*)(rp);
        short8 b1 = *(const short8*)(rp + 32);
        floatx4 acc = {0.f,0.f,0.f,0.f};
        acc = __builtin_amdgcn_mfma_f32_16x16x32_bf16(qpf[0], b0, acc, 0,0,0);
        acc = __builtin_amdgcn_mfma_f32_16x16x32_bf16(qpf[1], b1, acc, 0,0,0);
        #pragma unroll
        for (int g = 0; g < 4; g++) {
            int row = quad*4 + g;
            int j = uu + i0 + row - 1024;
            if (j >= 0 && j < S_ && uu <= 2046)
                PSC[row*1024 + j] = f2bf(acc[g]);
        }
    }
    if (i0 == 0 && tid == 0) {
        float sdot = 0.f;
        const u16* r0p = R + (size_t)n*T_*DH;
        const u16* q1p = qq + hbase + DH;
        for (int d = 0; d < DH; d++)
            sdot += (bf2f(q1p[d]) + rrb[n*DH + d]*SCALEF) * bf2f(r0p[d]);
        PSC[1023] = f2bf(sdot);
    }
    __syncthreads();

    for (int rr = 0; rr < 4; rr++) {
        int r = wave*4 + rr;
        short8 c0 = *(const short8*)(SC  + r*1024 + lane*16);
        short8 c1 = *(const short8*)(SC  + r*1024 + lane*16 + 8);
        short8 p0 = *(const short8*)(PSC + r*1024 + lane*16);
        short8 p1 = *(const short8*)(PSC + r*1024 + lane*16 + 8);
        float p[16];
        float mx = -1e30f;
        #pragma unroll
        for (int q = 0; q < 8; q++) {
            p[q]   = bf2f((u16)c0[q]) + bf2f((u16)p0[q]);
            p[q+8] = bf2f((u16)c1[q]) + bf2f((u16)p1[q]);
        }
        #pragma unroll
        for (int q = 0; q < 16; q++) mx = fmaxf(mx, p[q]);
        #pragma unroll
        for (int off = 32; off; off >>= 1) mx = fmaxf(mx, __shfl_xor(mx, off));
        float ssum = 0.f;
        #pragma unroll
        for (int q = 0; q < 16; q++) { p[q] = __expf(p[q] - mx); ssum += p[q]; }
        #pragma unroll
        for (int off = 32; off; off >>= 1) ssum += __shfl_xor(ssum, off);
        float inv = 1.0f / ssum;
        int swz = r & 7;
        union { u16 h[8]; short8 v; } w0, w1;
        #pragma unroll
        for (int q = 0; q < 8; q++) {
            w0.h[q] = f2bf(p[q]*inv);
            w1.h[q] = f2bf(p[q+8]*inv);
        }
        *(short8*)(SC + r*1024 + (((2*lane)   ^ swz) << 3)) = w0.v;
        *(short8*)(SC + r*1024 + (((2*lane+1) ^ swz) << 3)) = w1.v;
    }

    int d0 = wave*16;
    const u16* vbase = vt + ((size_t)bn*DH + d0 + qm)*S_;
    short8 vb[8];
    #pragma unroll
    for (int t = 0; t < 8; t++) vb[t] = *(const short8*)(vbase + t*32 + k8);
    __syncthreads();

    floatx4 o[4];
    #pragma unroll
    for (int t = 0; t < 4; t++) o[t] = (floatx4){0.f,0.f,0.f,0.f};
    int aswz = qm & 7;
    #pragma unroll
    for (int kt = 0; kt < 32; kt++) {
        short8 bfr = vb[kt & 7];
        if (kt < 24) vb[kt & 7] = *(const short8*)(vbase + (kt + 8)*32 + k8);
        int chunk = (kt*4 + quad) ^ aswz;
        short8 a = *(const short8*)(SC + qm*1024 + (chunk << 3));
        o[kt & 3] = __builtin_amdgcn_mfma_f32_16x16x32_bf16(a, bfr, o[kt & 3], 0,0,0);
    }
    floatx4 os = (o[0] + o[1]) + (o[2] + o[3]);
    #pragma unroll
    for (int g = 0; g < 4; g++) {
        int row = quad*4 + g;
        av[((size_t)(b*S_) + i0 + row)*D_ + n*DH + d0 + qm] = f2bf(os[g]);
    }
}

// ---------------- Kernel E: in-place LayerNorm (float4 I/O) ----------------
__global__ __launch_bounds__(256) void ln_kernel(
    const float* __restrict__ gamma, const float* __restrict__ beta,
    float* out)
{
    __shared__ float hb[8][D_];
    int tid = threadIdx.x;
    int rowg0 = blockIdx.x * 8;
    #pragma unroll
    for (int p = 0; p < 6; p++) {
        int id = p*256 + tid;
        int r = id / 192, e4 = id % 192;
        *(float4*)&hb[r][e4*4] = *(const float4*)&out[(size_t)(rowg0 + r)*D_ + e4*4];
    }
    __syncthreads();
    int wave = tid >> 6, lane = tid & 63;
    for (int rr = 0; rr < 2; rr++) {
        int r = wave*2 + rr;
        float s = 0.f;
        #pragma unroll
        for (int kq = 0; kq < 12; kq++) s += hb[r][lane + kq*64];
        #pragma unroll
        for (int off = 32; off; off >>= 1) s += __shfl_xor(s, off);
        float mu = s * (1.0f/768.0f);
        float vsum = 0.f;
        #pragma unroll
        for (int kq = 0; kq < 12; kq++) { float d = hb[r][lane + kq*64] - mu; vsum += d*d; }
        #pragma unroll
        for (int off = 32; off; off >>= 1) vsum += __shfl_xor(vsum, off);
        float rstd = rsqrtf(vsum * (1.0f/768.0f) + 1e-9f);
        #pragma unroll
        for (int kq = 0; kq < 3; kq++) {
            int c4 = lane + kq*64;
            float4 g4 = *(const float4*)&gamma[c4*4];
            float4 b4 = *(const float4*)&beta[c4*4];
            float4 h4 = *(const float4*)&hb[r][c4*4];
            float4 o4;
            o4.x = (h4.x - mu)*rstd*g4.x + b4.x;
            o4.y = (h4.y - mu)*rstd*g4.y + b4.y;
            o4.z = (h4.z - mu)*rstd*g4.z + b4.z;
            o4.w = (h4.w - mu)*rstd*g4.w + b4.w;
            *(float4*)&out[(size_t)(rowg0 + r)*D_ + c4*4] = o4;
        }
    }
}

extern "C" void kernel_launch(void* const* d_in, const int* in_sizes, int n_in,
                              void* d_out, int out_size, void* d_ws, size_t ws_size,
                              hipStream_t stream) {
    const float* query = (const float*)d_in[0];
    const float* pe    = (const float*)d_in[1];
    const float* Wq    = (const float*)d_in[2];
    const float* Wk    = (const float*)d_in[3];
    const float* bk    = (const float*)d_in[4];
    const float* Wv    = (const float*)d_in[5];
    const float* bv    = (const float*)d_in[6];
    const float* rk    = (const float*)d_in[7];
    const float* rwb   = (const float*)d_in[8];
    const float* rrb   = (const float*)d_in[9];
    const float* Wo    = (const float*)d_in[10];
    const float* bo    = (const float*)d_in[11];
    const float* gamma = (const float*)d_in[12];
    const float* beta  = (const float*)d_in[13];
    float* out = (float*)d_out;

    u16* ws = (u16*)d_ws;
    const size_t SEG = (size_t)B_*H_*S_*DH;       // 1,572,864 elems
    u16* qq  = ws;                 // [bn][s][d]
    u16* kk  = qq + SEG;           // [bn][s][d]
    u16* vt  = kk + SEG;           // [bn][d][s]
    u16* R   = vt + SEG;           // [n][2047][d]
    u16* qb  = R  + SEG;           // bf16 query [2048][768]; later reused as av
    u16* WoT = qb + SEG;           // [768][768] bf16 (transposed Wo)
    u16* WqT = WoT + (size_t)D_*D_;          // [4][192][192]
    u16* WkT = WqT + (size_t)G_*DG*DG;
    u16* WvT = WkT + (size_t)G_*DG*DG;
    u16* av  = qb;                 // alias: qb dead after proj; attn writes av after

    // d_out scratch (dead until out-gemm writes h): peb + rkT
    u16* peb = (u16*)d_out;                    // bf16 pe [2047][768] (+pad row)
    u16* rkT = peb + SEG;                      // [768][768] bf16 (transposed rk)

    conv_kernel<<<768, 256, 0, stream>>>(query, pe, qb, peb);
    trans_kernel<<<dim3(12,12,5), 256, 0, stream>>>(rk, Wo, Wq, Wk, Wv, rkT, WoT, WqT, WkT, WvT);
    proj_kernel<<<dim3(32,12), 256, 0, stream>>>(qb, WqT, WkT, WvT, bk, bv, qq, kk, vt);
    gemm_kernel<0><<<dim3(32,12), 256, 0, stream>>>(peb, rkT, nullptr, nullptr, R, nullptr, T_);
    attn_kernel<<<1536, 256, 0, stream>>>(qq, kk, vt, R, rwb, rrb, av);
    gemm_kernel<1><<<dim3(32,12), 256, 0, stream>>>(av, WoT, bo, query, nullptr, out, B_*S_);
    ln_kernel<<<256, 256, 0, stream>>>(gamma, beta, out);
}

// Round 11
// 210.409 us; speedup vs baseline: 1.0206x; 1.0206x over previous
//
#include <hip/hip_runtime.h>
#include <stdint.h>

#define B_ 2
#define S_ 1024
#define D_ 768
#define H_ 12
#define DH 64
#define G_ 4
#define DG 192
#define T_ 2047
#define SCALEF 0.125f

typedef unsigned short u16;
typedef unsigned int u32;
typedef __attribute__((ext_vector_type(8))) short short8;
typedef __attribute__((ext_vector_type(4))) float floatx4;

__device__ __forceinline__ float uas(u32 x){ union { u32 i; float f; } v; v.i = x; return v.f; }
__device__ __forceinline__ float bf2f(u16 u){ return uas(((u32)u) << 16); }
__device__ __forceinline__ u16 f2bf(float f){
    union { float f; u32 i; } v; v.f = f;
    u32 x = v.i;
    u32 r = (x + 0x7fffu + ((x >> 16) & 1u)) >> 16;  // RNE
    return (u16)r;
}

// ---------------- Kernel PRE: merged proj (blocks 0..383) + rhead gemm (384..1151) ----
// proj: grouped q/k/v via MFMA, fp32 W staged->bf16 (round-9 body).
// rhead: pe[2047,768] @ rk -> bf16 R[n][t][d] (round-9 gemm EPI0 body, BM64/BN32/BK64).
__global__ __launch_bounds__(256) void pre_kernel(
    const float* __restrict__ query,
    const float* __restrict__ Wq, const float* __restrict__ Wk, const float* __restrict__ Wv,
    const float* __restrict__ bk, const float* __restrict__ bv,
    u16* __restrict__ qq, u16* __restrict__ ko, u16* __restrict__ vt,
    const float* __restrict__ pe, const float* __restrict__ rk,
    u16* __restrict__ R)
{
    __shared__ __align__(16) char sm[19712];
    int tid  = threadIdx.x;
    int wave = tid >> 6, lane = tid & 63;
    int qm   = lane & 15;
    int quad = lane >> 4;
    int k8   = quad * 8;
    int id = blockIdx.x;

    if (id < 384) {
        // ================= proj body =================
        typedef u16 (*AsT)[40];
        typedef u16 (*WsT)[64][38];
        AsT As = (AsT)sm;                          // [64][40]
        WsT Ws = (WsT)(sm + 64*40*2);              // [3][64][38]
        int m0 = (id & 31) * 64;
        int gy = id >> 5;
        int g  = gy / 3;
        int n0 = (gy % 3) * 64;

        const float* Wm[3] = { Wq, Wk, Wv };

        floatx4 acc[3][4];
        #pragma unroll
        for (int md = 0; md < 3; md++)
            #pragma unroll
            for (int bt = 0; bt < 4; bt++) acc[md][bt] = (floatx4){0.f,0.f,0.f,0.f};

        for (int kt = 0; kt < 6; kt++) {
            int k0 = kt * 32;
            #pragma unroll
            for (int p = 0; p < 8; p++) {
                int idx = p*256 + tid;
                int m = idx >> 5, k = idx & 31;
                As[m][k] = f2bf(query[(size_t)(m0 + m)*D_ + g*DG + k0 + k]);
            }
            #pragma unroll
            for (int md = 0; md < 3; md++) {
                const float* W = Wm[md] + (size_t)g*DG*DG;
                #pragma unroll
                for (int p = 0; p < 8; p++) {
                    int k = p*4 + (tid >> 6);
                    int n = tid & 63;
                    Ws[md][n][k] = f2bf(W[(size_t)(k0 + k)*DG + n0 + n]);
                }
            }
            __syncthreads();
            short8 a = *(const short8*)&As[wave*16 + qm][k8];
            #pragma unroll
            for (int md = 0; md < 3; md++) {
                #pragma unroll
                for (int bt = 0; bt < 4; bt++) {
                    short8 b = *(const short8*)&Ws[md][bt*16 + qm][k8];
                    acc[md][bt] = __builtin_amdgcn_mfma_f32_16x16x32_bf16(a, b, acc[md][bt], 0,0,0);
                }
            }
            __syncthreads();
        }

        int rowbase = m0 + wave*16 + quad*4;
        int b  = rowbase >> 10;
        int s0 = rowbase & 1023;
        #pragma unroll
        for (int bt = 0; bt < 4; bt++) {
            int c = g*DG + n0 + bt*16 + qm;
            int n = c >> 6, d = c & 63;
            int bn = b*H_ + n;
            float bkv = bk[c], bvv = bv[c];
            #pragma unroll
            for (int gg = 0; gg < 4; gg++) {
                size_t o = ((size_t)bn*S_ + s0 + gg)*DH + d;
                qq[o] = f2bf(acc[0][bt][gg]*SCALEF);
                ko[o] = f2bf(acc[1][bt][gg] + bkv);
            }
            union { u16 h[4]; uint2 v; } vv;
            #pragma unroll
            for (int gg = 0; gg < 4; gg++) vv.h[gg] = f2bf(acc[2][bt][gg] + bvv);
            *(uint2*)(vt + ((size_t)bn*DH + d)*S_ + s0) = vv.v;
        }
    } else {
        // ================= rhead gemm body (A=pe fp32, W=rk fp32, EPI0) =================
        typedef u16 (*AsT)[72];
        AsT As = (AsT)sm;                          // [64][72]
        AsT Ws = (AsT)(sm + 64*72*2);              // [32][72]
        int id2 = id - 384;
        int m0 = (id2 & 31) * 64;
        int n0 = (id2 >> 5) * 32;
        int wn = tid & 31, wk = tid >> 5;
        const int Mvalid = T_;

        float4 af[4]; float wf[8];
        floatx4 acc[2];
        acc[0] = (floatx4){0.f,0.f,0.f,0.f};
        acc[1] = (floatx4){0.f,0.f,0.f,0.f};

        #pragma unroll
        for (int p = 0; p < 4; p++) {
            int idd = p*256 + tid; int m = idd >> 4, kq = idd & 15;
            int row = m0 + m; if (row >= Mvalid) row = Mvalid - 1;
            af[p] = *(const float4*)(pe + (size_t)row*D_ + kq*4);
        }
        #pragma unroll
        for (int p = 0; p < 8; p++) wf[p] = rk[(size_t)(wk*8 + p)*D_ + n0 + wn];

        for (int kt = 0; kt < 12; kt++) {
            __syncthreads();
            #pragma unroll
            for (int p = 0; p < 4; p++) {
                int idd = p*256 + tid; int m = idd >> 4, kq = idd & 15;
                union { u16 h[4]; uint2 v; } u;
                u.h[0] = f2bf(af[p].x); u.h[1] = f2bf(af[p].y);
                u.h[2] = f2bf(af[p].z); u.h[3] = f2bf(af[p].w);
                *(uint2*)&As[m][kq*4] = u.v;
            }
            {
                union { u16 h[8]; short8 v; } w8;
                #pragma unroll
                for (int p = 0; p < 8; p++) w8.h[p] = f2bf(wf[p]);
                *(short8*)&Ws[wn][wk*8] = w8.v;
            }
            __syncthreads();
            if (kt < 11) {
                int k0 = (kt + 1) * 64;
                #pragma unroll
                for (int p = 0; p < 4; p++) {
                    int idd = p*256 + tid; int m = idd >> 4, kq = idd & 15;
                    int row = m0 + m; if (row >= Mvalid) row = Mvalid - 1;
                    af[p] = *(const float4*)(pe + (size_t)row*D_ + k0 + kq*4);
                }
                #pragma unroll
                for (int p = 0; p < 8; p++) wf[p] = rk[(size_t)(k0 + wk*8 + p)*D_ + n0 + wn];
            }
            #pragma unroll
            for (int ks = 0; ks < 2; ks++) {
                short8 a = *(const short8*)&As[wave*16 + qm][ks*32 + k8];
                #pragma unroll
                for (int bt = 0; bt < 2; bt++) {
                    short8 b = *(const short8*)&Ws[bt*16 + qm][ks*32 + k8];
                    acc[bt] = __builtin_amdgcn_mfma_f32_16x16x32_bf16(a, b, acc[bt], 0,0,0);
                }
            }
        }

        #pragma unroll
        for (int bt = 0; bt < 2; bt++) {
            int c = n0 + bt*16 + qm;
            #pragma unroll
            for (int g = 0; g < 4; g++) {
                int row = m0 + wave*16 + quad*4 + g;
                if (row < Mvalid)
                    R[((size_t)(c >> 6)*T_ + row)*DH + (c & 63)] = f2bf(acc[bt][g]);
            }
        }
    }
}

// ---------------- out GEMM: h = av(bf16) @ Wo + bo + query (fp32 out) ----------------
__global__ __launch_bounds__(256) void gemm_out_kernel(
    const u16* __restrict__ A, const float* __restrict__ W,
    const float* __restrict__ bias, const float* __restrict__ resid,
    float* __restrict__ outf)
{
    __shared__ u16 As[64][72];
    __shared__ u16 Ws[32][72];
    int tid  = threadIdx.x;
    int wave = tid >> 6, lane = tid & 63;
    int qm   = lane & 15;
    int quad = lane >> 4;
    int k8   = quad * 8;
    int m0 = blockIdx.x * 64;
    int n0 = blockIdx.y * 32;
    int wn = tid & 31, wk = tid >> 5;

    short8 ab[2]; float wf[8];
    floatx4 acc[2];
    acc[0] = (floatx4){0.f,0.f,0.f,0.f};
    acc[1] = (floatx4){0.f,0.f,0.f,0.f};

    #pragma unroll
    for (int p = 0; p < 2; p++) {
        int id = p*256 + tid; int m = id >> 3, kq = id & 7;
        ab[p] = *(const short8*)(A + (size_t)(m0+m)*D_ + kq*8);
    }
    #pragma unroll
    for (int p = 0; p < 8; p++) wf[p] = W[(size_t)(wk*8 + p)*D_ + n0 + wn];

    for (int kt = 0; kt < 12; kt++) {
        __syncthreads();
        #pragma unroll
        for (int p = 0; p < 2; p++) {
            int id = p*256 + tid; int m = id >> 3, kq = id & 7;
            *(short8*)&As[m][kq*8] = ab[p];
        }
        {
            union { u16 h[8]; short8 v; } w8;
            #pragma unroll
            for (int p = 0; p < 8; p++) w8.h[p] = f2bf(wf[p]);
            *(short8*)&Ws[wn][wk*8] = w8.v;
        }
        __syncthreads();
        if (kt < 11) {
            int k0 = (kt + 1) * 64;
            #pragma unroll
            for (int p = 0; p < 2; p++) {
                int id = p*256 + tid; int m = id >> 3, kq = id & 7;
                ab[p] = *(const short8*)(A + (size_t)(m0+m)*D_ + k0 + kq*8);
            }
            #pragma unroll
            for (int p = 0; p < 8; p++) wf[p] = W[(size_t)(k0 + wk*8 + p)*D_ + n0 + wn];
        }
        #pragma unroll
        for (int ks = 0; ks < 2; ks++) {
            short8 a = *(const short8*)&As[wave*16 + qm][ks*32 + k8];
            #pragma unroll
            for (int bt = 0; bt < 2; bt++) {
                short8 b = *(const short8*)&Ws[bt*16 + qm][ks*32 + k8];
                acc[bt] = __builtin_amdgcn_mfma_f32_16x16x32_bf16(a, b, acc[bt], 0,0,0);
            }
        }
    }

    #pragma unroll
    for (int bt = 0; bt < 2; bt++) {
        int c = n0 + bt*16 + qm;
        #pragma unroll
        for (int g = 0; g < 4; g++) {
            int row = m0 + wave*16 + quad*4 + g;
            outf[(size_t)row*D_ + c] = acc[bt][g] + bias[c] + resid[(size_t)row*D_ + c];
        }
    }
}

// ---------------- Kernel C: MFMA fused rel-attention v4 (unchanged, verified) ----------------
__global__ __launch_bounds__(256, 2) void attn_kernel(
    const u16* __restrict__ qq,
    const u16* __restrict__ kk, const u16* __restrict__ vt,
    const u16* __restrict__ R,
    const float* __restrict__ rwb, const float* __restrict__ rrb,
    u16* __restrict__ av)
{
    __shared__ char smem[64*1024];
    u16* SC  = (u16*)smem;            // [16][1024] content scores -> probs
    u16* PSC = (u16*)(smem + 32768);  // [16][1024] pos scores
    int tid  = threadIdx.x;
    int wave = tid >> 6, lane = tid & 63;
    int qm   = lane & 15;
    int quad = lane >> 4;
    int k8   = quad * 8;
    int blkid = blockIdx.x;
    int xcd = blkid & 7;
    int sl  = blkid >> 3;
    int it  = sl & 63;
    int seg = sl >> 6;
    int bn  = xcd + 8*seg;
    int b = bn / H_, n = bn % H_;
    int i0 = it * 16;
    size_t hbase = (size_t)bn * S_ * DH;

    short8 qcf[2], qpf[2];
    #pragma unroll
    for (int s = 0; s < 2; s++) {
        const u16* qptr = qq + hbase + (size_t)(i0 + qm)*DH + s*32 + k8;
        const float* rwp = rwb + n*DH + s*32 + k8;
        const float* rrp = rrb + n*DH + s*32 + k8;
        #pragma unroll
        for (int j = 0; j < 8; j++) {
            float qv = bf2f(qptr[j]);
            qcf[s][j] = (short)f2bf(qv + rwp[j]*SCALEF);
            qpf[s][j] = (short)f2bf(qv + rrp[j]*SCALEF);
        }
    }

    {
        const u16* kbb = kk + hbase + (size_t)qm*DH + k8;
        short8 rb[8][2];
        #pragma unroll
        for (int t = 0; t < 8; t++) {
            const u16* kp = kbb + (size_t)((wave*16 + t)*16)*DH;
            rb[t][0] = *(const short8*)(kp);
            rb[t][1] = *(const short8*)(kp + 32);
        }
        #pragma unroll
        for (int t = 0; t < 16; t++) {
            short8 b0 = rb[t & 7][0], b1 = rb[t & 7][1];
            if (t < 8) {
                const u16* kp = kbb + (size_t)((wave*16 + t + 8)*16)*DH;
                rb[t & 7][0] = *(const short8*)(kp);
                rb[t & 7][1] = *(const short8*)(kp + 32);
            }
            floatx4 acc = {0.f,0.f,0.f,0.f};
            acc = __builtin_amdgcn_mfma_f32_16x16x32_bf16(qcf[0], b0, acc, 0,0,0);
            acc = __builtin_amdgcn_mfma_f32_16x16x32_bf16(qcf[1], b1, acc, 0,0,0);
            int j0 = (wave*16 + t) * 16;
            #pragma unroll
            for (int g = 0; g < 4; g++)
                SC[(quad*4 + g)*1024 + j0 + qm] = f2bf(acc[g]);
        }
    }

    int ubase = 1008 - i0;
    {
        const u16* rbb = R + (size_t)n*T_*DH + k8;
        short8 rb[8][2];
        int us[8];
        #pragma unroll
        for (int t = 0; t < 8; t++) {
            int m = t*4 + wave;
            int uu = ubase + m*16 + qm;
            int ur = (uu <= 2046) ? uu : 2046;
            us[t] = uu;
            const u16* rp = rbb + (size_t)ur*DH;
            rb[t][0] = *(const short8*)(rp);
            rb[t][1] = *(const short8*)(rp + 32);
        }
        #pragma unroll
        for (int t = 0; t < 16; t++) {
            short8 b0 = rb[t & 7][0], b1 = rb[t & 7][1];
            int uu = us[t & 7];
            if (t < 8) {
                int m2 = (t + 8)*4 + wave;
                int uu2 = ubase + m2*16 + qm;
                int ur2 = (uu2 <= 2046) ? uu2 : 2046;
                us[t & 7] = uu2;
                const u16* rp = rbb + (size_t)ur2*DH;
                rb[t & 7][0] = *(const short8*)(rp);
                rb[t & 7][1] = *(const short8*)(rp + 32);
            }
            floatx4 acc = {0.f,0.f,0.f,0.f};
            acc = __builtin_amdgcn_mfma_f32_16x16x32_bf16(qpf[0], b0, acc, 0,0,0);
            acc = __builtin_amdgcn_mfma_f32_16x16x32_bf16(qpf[1], b1, acc, 0,0,0);
            #pragma unroll
            for (int g = 0; g < 4; g++) {
                int row = quad*4 + g;
                int j = uu + i0 + row - 1024;
                if (j >= 0 && j < S_ && uu <= 2046)
                    PSC[row*1024 + j] = f2bf(acc[g]);
            }
        }
    }
    if (wave == 0) {
        int uu = ubase + 64*16 + qm;
        int ur = (uu <= 2046) ? uu : 2046;
        const u16* rp = R + ((size_t)n*T_ + ur)*DH + k8;
        short8 b0 = *(const short8*)(rp);
        short8 b1 = *(const short8*)(rp + 32);
        floatx4 acc = {0.f,0.f,0.f,0.f};
        acc = __builtin_amdgcn_mfma_f32_16x16x32_bf16(qpf[0], b0, acc, 0,0,0);
        acc = __builtin_amdgcn_mfma_f32_16x16x32_bf16(qpf[1], b1, acc, 0,0,0);
        #pragma unroll
        for (int g = 0; g < 4; g++) {
            int row = quad*4 + g;
            int j = uu + i0 + row - 1024;
            if (j >= 0 && j < S_ && uu <= 2046)
                PSC[row*1024 + j] = f2bf(acc[g]);
        }
    }
    if (i0 == 0 && tid == 0) {
        float sdot = 0.f;
        const u16* r0p = R + (size_t)n*T_*DH;
        const u16* q1p = qq + hbase + DH;
        for (int d = 0; d < DH; d++)
            sdot += (bf2f(q1p[d]) + rrb[n*DH + d]*SCALEF) * bf2f(r0p[d]);
        PSC[1023] = f2bf(sdot);
    }
    __syncthreads();

    for (int rr = 0; rr < 4; rr++) {
        int r = wave*4 + rr;
        short8 c0 = *(const short8*)(SC  + r*1024 + lane*16);
        short8 c1 = *(const short8*)(SC  + r*1024 + lane*16 + 8);
        short8 p0 = *(const short8*)(PSC + r*1024 + lane*16);
        short8 p1 = *(const short8*)(PSC + r*1024 + lane*16 + 8);
        float p[16];
        float mx = -1e30f;
        #pragma unroll
        for (int q = 0; q < 8; q++) {
            p[q]   = bf2f((u16)c0[q]) + bf2f((u16)p0[q]);
            p[q+8] = bf2f((u16)c1[q]) + bf2f((u16)p1[q]);
        }
        #pragma unroll
        for (int q = 0; q < 16; q++) mx = fmaxf(mx, p[q]);
        #pragma unroll
        for (int off = 32; off; off >>= 1) mx = fmaxf(mx, __shfl_xor(mx, off));
        float ssum = 0.f;
        #pragma unroll
        for (int q = 0; q < 16; q++) { p[q] = __expf(p[q] - mx); ssum += p[q]; }
        #pragma unroll
        for (int off = 32; off; off >>= 1) ssum += __shfl_xor(ssum, off);
        float inv = 1.0f / ssum;
        int swz = r & 7;
        union { u16 h[8]; short8 v; } w0, w1;
        #pragma unroll
        for (int q = 0; q < 8; q++) {
            w0.h[q] = f2bf(p[q]*inv);
            w1.h[q] = f2bf(p[q+8]*inv);
        }
        *(short8*)(SC + r*1024 + (((2*lane)   ^ swz) << 3)) = w0.v;
        *(short8*)(SC + r*1024 + (((2*lane+1) ^ swz) << 3)) = w1.v;
    }

    int d0 = wave*16;
    const u16* vbase = vt + ((size_t)bn*DH + d0 + qm)*S_;
    short8 vb[8];
    #pragma unroll
    for (int t = 0; t < 8; t++) vb[t] = *(const short8*)(vbase + t*32 + k8);
    __syncthreads();

    floatx4 o[4];
    #pragma unroll
    for (int t = 0; t < 4; t++) o[t] = (floatx4){0.f,0.f,0.f,0.f};
    int aswz = qm & 7;
    #pragma unroll
    for (int kt = 0; kt < 32; kt++) {
        short8 bfr = vb[kt & 7];
        if (kt < 24) vb[kt & 7] = *(const short8*)(vbase + (kt + 8)*32 + k8);
        int chunk = (kt*4 + quad) ^ aswz;
        short8 a = *(const short8*)(SC + qm*1024 + (chunk << 3));
        o[kt & 3] = __builtin_amdgcn_mfma_f32_16x16x32_bf16(a, bfr, o[kt & 3], 0,0,0);
    }
    floatx4 os = (o[0] + o[1]) + (o[2] + o[3]);
    #pragma unroll
    for (int g = 0; g < 4; g++) {
        int row = quad*4 + g;
        av[((size_t)(b*S_) + i0 + row)*D_ + n*DH + d0 + qm] = f2bf(os[g]);
    }
}

// ---------------- Kernel E: in-place LayerNorm (float4 I/O) ----------------
__global__ __launch_bounds__(256) void ln_kernel(
    const float* __restrict__ gamma, const float* __restrict__ beta,
    float* out)
{
    __shared__ float hb[8][D_];
    int tid = threadIdx.x;
    int rowg0 = blockIdx.x * 8;
    #pragma unroll
    for (int p = 0; p < 6; p++) {
        int id = p*256 + tid;
        int r = id / 192, e4 = id % 192;
        *(float4*)&hb[r][e4*4] = *(const float4*)&out[(size_t)(rowg0 + r)*D_ + e4*4];
    }
    __syncthreads();
    int wave = tid >> 6, lane = tid & 63;
    for (int rr = 0; rr < 2; rr++) {
        int r = wave*2 + rr;
        float s = 0.f;
        #pragma unroll
        for (int kq = 0; kq < 12; kq++) s += hb[r][lane + kq*64];
        #pragma unroll
        for (int off = 32; off; off >>= 1) s += __shfl_xor(s, off);
        float mu = s * (1.0f/768.0f);
        float vsum = 0.f;
        #pragma unroll
        for (int kq = 0; kq < 12; kq++) { float d = hb[r][lane + kq*64] - mu; vsum += d*d; }
        #pragma unroll
        for (int off = 32; off; off >>= 1) vsum += __shfl_xor(vsum, off);
        float rstd = rsqrtf(vsum * (1.0f/768.0f) + 1e-9f);
        #pragma unroll
        for (int kq = 0; kq < 3; kq++) {
            int c4 = lane + kq*64;
            float4 g4 = *(const float4*)&gamma[c4*4];
            float4 b4 = *(const float4*)&beta[c4*4];
            float4 h4 = *(const float4*)&hb[r][c4*4];
            float4 o4;
            o4.x = (h4.x - mu)*rstd*g4.x + b4.x;
            o4.y = (h4.y - mu)*rstd*g4.y + b4.y;
            o4.z = (h4.z - mu)*rstd*g4.z + b4.z;
            o4.w = (h4.w - mu)*rstd*g4.w + b4.w;
            *(float4*)&out[(size_t)(rowg0 + r)*D_ + c4*4] = o4;
        }
    }
}

extern "C" void kernel_launch(void* const* d_in, const int* in_sizes, int n_in,
                              void* d_out, int out_size, void* d_ws, size_t ws_size,
                              hipStream_t stream) {
    const float* query = (const float*)d_in[0];
    const float* pe    = (const float*)d_in[1];
    const float* Wq    = (const float*)d_in[2];
    const float* Wk    = (const float*)d_in[3];
    const float* bk    = (const float*)d_in[4];
    const float* Wv    = (const float*)d_in[5];
    const float* bv    = (const float*)d_in[6];
    const float* rk    = (const float*)d_in[7];
    const float* rwb   = (const float*)d_in[8];
    const float* rrb   = (const float*)d_in[9];
    const float* Wo    = (const float*)d_in[10];
    const float* bo    = (const float*)d_in[11];
    const float* gamma = (const float*)d_in[12];
    const float* beta  = (const float*)d_in[13];
    float* out = (float*)d_out;

    u16* ws = (u16*)d_ws;
    const size_t SEG = (size_t)B_*H_*S_*DH;       // 1,572,864 elems (3 MB bf16)
    u16* qq = ws;             // [bn][s][d]
    u16* kk = qq + SEG;       // [bn][s][d]
    u16* vt = kk + SEG;       // [bn][d][s]  (transposed V)
    u16* R  = vt + SEG;       // [n][2047][d]
    u16* av = R + SEG;        // [b*S+s][n*64+d] bf16 attn_vec

    // merged proj (384 blocks) + rhead gemm (768 blocks)
    pre_kernel<<<1152, 256, 0, stream>>>(query, Wq, Wk, Wv, bk, bv, qq, kk, vt, pe, rk, R);
    attn_kernel<<<1536, 256, 0, stream>>>(qq, kk, vt, R, rwb, rrb, av);
    gemm_out_kernel<<<dim3(32,24), 256, 0, stream>>>(av, Wo, bo, query, out);
    ln_kernel<<<256, 256, 0, stream>>>(gamma, beta, out);
}